// Round 18
// baseline (344.302 us; speedup 1.0000x reference)
//
#include <hip/hip_runtime.h>
#include <hip/hip_bf16.h>

typedef float f32x4 __attribute__((ext_vector_type(4)));
typedef __bf16 bf16x8 __attribute__((ext_vector_type(8)));
typedef unsigned short u16x4 __attribute__((ext_vector_type(4)));

__device__ __forceinline__ unsigned short f2bf(float f) {
  unsigned u = __builtin_bit_cast(unsigned, f);
  u += 0x7FFFu + ((u >> 16) & 1u);
  return (unsigned short)(u >> 16);
}
__device__ __forceinline__ float bf2f(unsigned short h) {
  unsigned u = ((unsigned)h) << 16;
  return __builtin_bit_cast(float, u);
}

__device__ __forceinline__ void gload_lds16(const void* g, void* l) {
  __builtin_amdgcn_global_load_lds(
      (const __attribute__((address_space(1))) void*)g,
      (__attribute__((address_space(3))) void*)l, 16, 0, 0);
}

// ------------- 256x256 2-phase-per-K-tile bf16 GEMM (r13 base) --------------
// C[m][n] = scale * sum_k A[m][k]*B[n][k] (+ bias[n]). A:[M][K], B:[N][K] bf16.
// r17 verbatim (FMODEs for fused softmax partials). Used for QK^T (OUT 3) and
// PV (OUT 2) this round; projections move to gemmP below.
constexpr int BM = 256, BN = 256, BK = 64;

#define BAR() __builtin_amdgcn_s_barrier()
#define LGKM0()                                        \
  do {                                                 \
    asm volatile("s_waitcnt lgkmcnt(0)" ::: "memory"); \
    __builtin_amdgcn_sched_barrier(0);                 \
  } while (0)
#define VMW(N) asm volatile("s_waitcnt vmcnt(" #N ")" ::: "memory")
#define PRIO(x) __builtin_amdgcn_s_setprio(x)

#define MM(a_, b_, c_)                                                        \
  c_ = __builtin_amdgcn_mfma_f32_16x16x32_bf16(                               \
      __builtin_bit_cast(bf16x8, a_), __builtin_bit_cast(bf16x8, b_), c_, 0, 0, 0)

template <int OUT_MODE, bool HAS_BIAS, int FMODE>
__global__ __launch_bounds__(512, 2) void gemm256(
    const unsigned short* __restrict__ A, const unsigned short* __restrict__ B,
    const float* __restrict__ bias, float scale, void* __restrict__ Cv,
    int N, int K, long sA, long sB, long sC, float* __restrict__ rsum,
    int gx, int gy) {
  __shared__ char sm[131072];

  const int nwg = gridDim.x;
  int id = blockIdx.x;
  id = (id & 7) * (nwg >> 3) + (id >> 3);  // XCD swizzle (nwg % 8 == 0)
  const int bx = id % gx;
  const int by = (id / gx) % gy;
  const int bz = id / (gx * gy);

  const int t = threadIdx.x;
  const int lane = t & 63;
  const int w = t >> 6;
  const int wm = w >> 2;
  const int wn = w & 3;

  const int rowBase = by * BM;
  const int colBase = bx * BN;
  const unsigned short* Ab = A + sA * bz;
  const unsigned short* Bb = B + sB * bz;
  const int NT = K >> 6;

  const int srl = lane >> 3;
  const int schunk = (lane & 7) ^ srl;

#define STAGE_A(tt, h, d)                                                     \
  do {                                                                        \
    int _kt = (tt); if (_kt > NT - 1) _kt = NT - 1;                           \
    const int _k0 = _kt << 6;                                                 \
    _Pragma("unroll") for (int _j = 0; _j < 2; ++_j) {                        \
      const int _r = (w + 8 * _j) * 8 + srl;                                  \
      gload_lds16(Ab + (size_t)(rowBase + (h) * 128 + _r) * K + _k0 + schunk * 8, \
                  sm + (d) * 32768 + (h) * 16384 + (w + 8 * _j) * 1024);      \
    }                                                                         \
  } while (0)
#define STAGE_B(tt, h, d)                                                     \
  do {                                                                        \
    int _kt = (tt); if (_kt > NT - 1) _kt = NT - 1;                           \
    const int _k0 = _kt << 6;                                                 \
    _Pragma("unroll") for (int _j = 0; _j < 2; ++_j) {                        \
      const int _r = (w + 8 * _j) * 8 + srl;                                  \
      gload_lds16(Bb + (size_t)(colBase + (h) * 128 + _r) * K + _k0 + schunk * 8, \
                  sm + 65536 + (d) * 32768 + (h) * 16384 + (w + 8 * _j) * 1024); \
    }                                                                         \
  } while (0)

  const int lr = lane & 15;
  const int g0 = lane >> 4;
  const int sw0 = (g0 ^ (lr & 7)) << 4;
  const int sw1 = ((g0 + 4) ^ (lr & 7)) << 4;
  const int aBase = wm * 8192 + lr * 128;
  const int bBase = 65536 + wn * 4096 + lr * 128;

  uint4 Ar[4][2], Br0[2][2], Br1[2][2];
  f32x4 acc[8][4];
#pragma unroll
  for (int m = 0; m < 8; ++m)
#pragma unroll
    for (int n = 0; n < 4; ++n) acc[m][n] = (f32x4){0.f, 0.f, 0.f, 0.f};

#define READ_A(d, mh)                                                         \
  do {                                                                        \
    _Pragma("unroll") for (int f = 0; f < 4; ++f) {                           \
      Ar[f][0] = *(const uint4*)(sm + (d) * 32768 + (mh) * 16384 + aBase + f * 2048 + sw0); \
      Ar[f][1] = *(const uint4*)(sm + (d) * 32768 + (mh) * 16384 + aBase + f * 2048 + sw1); \
    }                                                                         \
  } while (0)
#define READ_B0(d)                                                            \
  do {                                                                        \
    _Pragma("unroll") for (int f = 0; f < 2; ++f) {                           \
      Br0[f][0] = *(const uint4*)(sm + (d) * 32768 + bBase + f * 2048 + sw0); \
      Br0[f][1] = *(const uint4*)(sm + (d) * 32768 + bBase + f * 2048 + sw1); \
    }                                                                         \
  } while (0)
#define READ_B1(d)                                                            \
  do {                                                                        \
    _Pragma("unroll") for (int f = 0; f < 2; ++f) {                           \
      Br1[f][0] = *(const uint4*)(sm + (d) * 32768 + 16384 + bBase + f * 2048 + sw0); \
      Br1[f][1] = *(const uint4*)(sm + (d) * 32768 + 16384 + bBase + f * 2048 + sw1); \
    }                                                                         \
  } while (0)

#define MFMA_Q(Bset, mh, nh)                                                  \
  do {                                                                        \
    _Pragma("unroll") for (int kk = 0; kk < 2; ++kk)                          \
        _Pragma("unroll") for (int mf = 0; mf < 4; ++mf)                      \
            _Pragma("unroll") for (int nf = 0; nf < 2; ++nf)                  \
                MM(Ar[mf][kk], Bset[nf][kk], acc[(mh) * 4 + mf][(nh) * 2 + nf]); \
  } while (0)

#define TILE2(t_, d_)                                                         \
  do {                                                                        \
    /* ph-A */ READ_B0(d_); READ_B1(d_); READ_A(d_, 0);                       \
    STAGE_A((t_) + 1, 1, (d_) ^ 1);                                           \
    BAR();                                                                    \
    PRIO(1); MFMA_Q(Br0, 0, 0); MFMA_Q(Br1, 0, 1); PRIO(0);                   \
    BAR();                                                                    \
    /* ph-B */ READ_A(d_, 1);                                                 \
    STAGE_A((t_) + 2, 0, d_); STAGE_B((t_) + 2, 0, d_); STAGE_B((t_) + 2, 1, d_); \
    BAR();                                                                    \
    PRIO(1); MFMA_Q(Br1, 1, 1); MFMA_Q(Br0, 1, 0); PRIO(0);                   \
    VMW(6);                                                                   \
    BAR();                                                                    \
  } while (0)

  STAGE_A(0, 0, 0); STAGE_B(0, 0, 0); STAGE_B(0, 1, 0); STAGE_A(0, 1, 0);
  STAGE_A(1, 0, 1); STAGE_B(1, 0, 1); STAGE_B(1, 1, 1);
  VMW(6);
  BAR();

  for (int i = 0; i < (NT >> 1); ++i) {
    TILE2(2 * i, 0);
    TILE2(2 * i + 1, 1);
  }
  VMW(0);

  // Epilogue. acc[m][n]: row = (m>>2)*128 + wm*64 + (m&3)*16 + g0*4 + r,
  //                      col = (n>>1)*128 + wn*32 + (n&1)*16 + lr.
  if constexpr (OUT_MODE == 3 && FMODE > 0) {
    unsigned short* C = (unsigned short*)Cv + sC * bz;
    float* smf = (float*)sm;
    if constexpr (FMODE == 1) __syncthreads();
#pragma unroll
    for (int m = 0; m < 8; ++m) {
      const int row0 = rowBase + (m >> 2) * 128 + wm * 64 + (m & 3) * 16 + g0 * 4;
      f32x4 rs = (f32x4){0.f, 0.f, 0.f, 0.f};
#pragma unroll
      for (int n = 0; n < 4; ++n) {
        const int col = colBase + (n >> 1) * 128 + wn * 32 + (n & 1) * 16 + lr;
        f32x4 v = acc[m][n];
#pragma unroll
        for (int r = 0; r < 4; ++r) {
          const unsigned short h = f2bf(__expf(v[r] * scale));
          C[(size_t)(row0 + r) * N + col] = h;
          rs[r] += bf2f(h);
        }
      }
#pragma unroll
      for (int mk = 1; mk < 16; mk <<= 1) {
        rs[0] += __shfl_xor(rs[0], mk);
        rs[1] += __shfl_xor(rs[1], mk);
        rs[2] += __shfl_xor(rs[2], mk);
        rs[3] += __shfl_xor(rs[3], mk);
      }
      if (lr == 0) {
        if constexpr (FMODE == 2) {
#pragma unroll
          for (int r = 0; r < 4; ++r)
            rsum[((size_t)bz * 2048 + row0 + r) * 32 + bx * 4 + wn] = rs[r];
        } else {
          const int lrow = row0 - rowBase;
#pragma unroll
          for (int r = 0; r < 4; ++r) smf[wn * 256 + lrow + r] = rs[r];
        }
      }
    }
    if constexpr (FMODE == 1) {
      __syncthreads();
      if (t < 256) {
        const float s4 = smf[t] + smf[256 + t] + smf[512 + t] + smf[768 + t];
        rsum[((size_t)bz * 2048 + rowBase + t) * 8 + bx] = s4;
      }
    }
  } else if constexpr (OUT_MODE == 3) {
    unsigned short* C = (unsigned short*)Cv + sC * bz;
#pragma unroll
    for (int n = 0; n < 4; ++n) {
      const int col = colBase + (n >> 1) * 128 + wn * 32 + (n & 1) * 16 + lr;
#pragma unroll
      for (int m = 0; m < 8; ++m) {
        const int row0 = rowBase + (m >> 2) * 128 + wm * 64 + (m & 3) * 16 + g0 * 4;
        f32x4 v = acc[m][n];
#pragma unroll
        for (int r = 0; r < 4; ++r)
          C[(size_t)(row0 + r) * N + col] = f2bf(__expf(v[r] * scale));
      }
    }
  } else if constexpr (OUT_MODE == 2) {
    float* C = (float*)Cv + sC * bz;
    float* smf = (float*)sm;
    if constexpr (FMODE == 2) {
      __syncthreads();
      if (t < 256) {
        const size_t pb = ((size_t)bz * 2048 + rowBase + t) * 32;
        float s = 0.f;
#pragma unroll
        for (int q = 0; q < 8; ++q) {
          const float4 p = *(const float4*)&rsum[pb + q * 4];
          s += ((p.x + p.y) + (p.z + p.w));
        }
        smf[t] = 1.f / s;
      }
      __syncthreads();
    }
#pragma unroll
    for (int m = 0; m < 8; ++m) {
      const int row0 = rowBase + (m >> 2) * 128 + wm * 64 + (m & 3) * 16 + g0 * 4;
      f32x4 inv;
      if constexpr (FMODE == 2) {
        const int lrow = row0 - rowBase;
#pragma unroll
        for (int r = 0; r < 4; ++r) inv[r] = smf[lrow + r];
      } else if constexpr (FMODE == 1) {
#pragma unroll
        for (int r = 0; r < 4; ++r) {
          const size_t pb = ((size_t)bz * 2048 + row0 + r) * 8;
          const float4 p0 = *(const float4*)&rsum[pb];
          const float4 p1 = *(const float4*)&rsum[pb + 4];
          inv[r] = 1.f / (((p0.x + p0.y) + (p0.z + p0.w)) +
                          ((p1.x + p1.y) + (p1.z + p1.w)));
        }
      } else {
        const float4 lv = *(const float4*)&rsum[(size_t)bz * 2048 + row0];
        inv[0] = 1.f / lv.x; inv[1] = 1.f / lv.y;
        inv[2] = 1.f / lv.z; inv[3] = 1.f / lv.w;
      }
#pragma unroll
      for (int n = 0; n < 4; ++n) {
        const int col = colBase + (n >> 1) * 128 + wn * 32 + (n & 1) * 16 + lr;
        f32x4 v = acc[m][n];
#pragma unroll
        for (int r = 0; r < 4; ++r)
          C[(size_t)(row0 + r) * N + col] = v[r] * inv[r];
      }
    }
  } else {
#pragma unroll
    for (int n = 0; n < 4; ++n) {
      const int col = colBase + (n >> 1) * 128 + wn * 32 + (n & 1) * 16 + lr;
      float bvv = 0.f;
      if constexpr (HAS_BIAS) bvv = bias[col];
#pragma unroll
      for (int m = 0; m < 8; ++m) {
        const int row0 = rowBase + (m >> 2) * 128 + wm * 64 + (m & 3) * 16 + g0 * 4;
        f32x4 v = acc[m][n];
        if constexpr (OUT_MODE == 0) {
          unsigned short* C = (unsigned short*)Cv + sC * bz;
#pragma unroll
          for (int r = 0; r < 4; ++r)
            C[(size_t)(row0 + r) * N + col] = f2bf(v[r] * scale + bvv);
        } else {
          unsigned short* C = (unsigned short*)Cv;
          const int b = row0 >> 11, s = row0 & 2047;
          u16x4 pk;
#pragma unroll
          for (int r = 0; r < 4; ++r) pk[r] = f2bf(v[r] * scale + bvv);
          *(u16x4*)&C[((size_t)b * N + col) * 2048 + s] = pk;
        }
      }
    }
  }
}

// ---- Projection GEMM v2: A fp32 reg-staged with fused fp32->bf16 -----------
// C = A @ Bw^T + bias. A: fp32 [M][K]; Bw: bf16 [N][K] (pre-converted W).
// r13 TILE2 skeleton; A-path: LOAD_AP (8x float4, issued a full tile ahead at
// ph-A) -> CVTW (cvt + swizzled ds_write_b128, next ph-A) -> LGKM0 publish.
// Mixed vmcnt ledger (per tile: 8 AP loads ph-A + 4 B gloads ph-B): VMW(12)
// at ph-B end retires exactly B(i+1) (oldest), floats AP(i+2)+B(i+2).
// __launch_bounds__(512, 1): LDS (128 KiB) caps residency at 1 block/CU
// anyway, so give the allocator the full register file -> no r9-style spill.
template <int OUT_MODE>
__global__ __launch_bounds__(512, 1) void gemmP(
    const float* __restrict__ Ap, const unsigned short* __restrict__ Bw,
    const float* __restrict__ bias, void* __restrict__ Cv, int N, int K,
    int gx, int gy) {
  __shared__ char sm[131072];

  const int nwg = gridDim.x;
  int id = blockIdx.x;
  id = (id & 7) * (nwg >> 3) + (id >> 3);  // XCD swizzle
  const int bx = id % gx;
  const int by = (id / gx) % gy;

  const int t = threadIdx.x;
  const int lane = t & 63;
  const int w = t >> 6;
  const int wm = w >> 2;
  const int wn = w & 3;

  const int rowBase = by * BM;
  const int colBase = bx * BN;
  const unsigned short* Bb = Bw;  // STAGE_B expects Bb
  const int NT = K >> 6;

  const int srl = lane >> 3;
  const int schunk = (lane & 7) ^ srl;

  // A staging roles: thread t -> row ar (both halves), slots as0, as0+1.
  const int ar = t >> 2;        // 0..127
  const int as0 = (t & 3) * 2;  // 0,2,4,6

  const int lr = lane & 15;
  const int g0 = lane >> 4;
  const int sw0 = (g0 ^ (lr & 7)) << 4;
  const int sw1 = ((g0 + 4) ^ (lr & 7)) << 4;
  const int aBase = wm * 8192 + lr * 128;
  const int bBase = 65536 + wn * 4096 + lr * 128;

  uint4 Ar[4][2], Br0[2][2], Br1[2][2];
  float4 Areg[2][4];  // [half][slotj*2 + (lo/hi float4)]
  f32x4 acc[8][4];
#pragma unroll
  for (int m = 0; m < 8; ++m)
#pragma unroll
    for (int n = 0; n < 4; ++n) acc[m][n] = (f32x4){0.f, 0.f, 0.f, 0.f};

#define LOAD_AP(tt)                                                           \
  do {                                                                        \
    int _kt = (tt); if (_kt > NT - 1) _kt = NT - 1;                           \
    _Pragma("unroll") for (int _h = 0; _h < 2; ++_h) {                        \
      const float* _ap = Ap + (size_t)(rowBase + _h * 128 + ar) * K +         \
                         (_kt << 6) + as0 * 8;                                \
      _Pragma("unroll") for (int _j = 0; _j < 2; ++_j) {                      \
        Areg[_h][_j * 2 + 0] = *(const float4*)(_ap + _j * 8);                \
        Areg[_h][_j * 2 + 1] = *(const float4*)(_ap + _j * 8 + 4);            \
      }                                                                       \
    }                                                                         \
  } while (0)

#define CVTW_AP(d)                                                            \
  do {                                                                        \
    _Pragma("unroll") for (int _h = 0; _h < 2; ++_h)                          \
      _Pragma("unroll") for (int _j = 0; _j < 2; ++_j) {                      \
        unsigned short _hh[8];                                                \
        const float4 _a = Areg[_h][_j * 2 + 0];                               \
        const float4 _b = Areg[_h][_j * 2 + 1];                               \
        _hh[0] = f2bf(_a.x); _hh[1] = f2bf(_a.y);                             \
        _hh[2] = f2bf(_a.z); _hh[3] = f2bf(_a.w);                             \
        _hh[4] = f2bf(_b.x); _hh[5] = f2bf(_b.y);                             \
        _hh[6] = f2bf(_b.z); _hh[7] = f2bf(_b.w);                             \
        const int _slot = as0 + _j;                                           \
        *(uint4*)(sm + (d) * 32768 + _h * 16384 + ar * 128 +                  \
                  ((_slot ^ (ar & 7)) << 4)) = *(uint4*)&_hh[0];              \
      }                                                                       \
  } while (0)

  // Per tile i (buf d=i&1):
  //  ph-A: ds_reads of B(i),A-h0(i); CVTW A(i+1)->d^1 (Areg from ph-A(i-1),
  //        region's reads retired >=2 barriers back); LOAD_AP A(i+2);
  //        LGKM0 (publish writes + drain reads); BAR; MFMA m0; BAR.
  //  ph-B: ds_read A-h1(i); STAGE_B(i+2)->d; BAR; MFMA m1; VMW(12); BAR.
#define TILE_P(t_, d_)                                                        \
  do {                                                                        \
    READ_B0(d_); READ_B1(d_); READ_A(d_, 0);                                  \
    CVTW_AP((d_) ^ 1);                                                        \
    LOAD_AP((t_) + 2);                                                        \
    LGKM0();                                                                  \
    BAR();                                                                    \
    PRIO(1); MFMA_Q(Br0, 0, 0); MFMA_Q(Br1, 0, 1); PRIO(0);                   \
    BAR();                                                                    \
    READ_A(d_, 1);                                                            \
    STAGE_B((t_) + 2, 0, d_); STAGE_B((t_) + 2, 1, d_);                       \
    BAR();                                                                    \
    PRIO(1); MFMA_Q(Br1, 1, 1); MFMA_Q(Br0, 1, 0); PRIO(0);                   \
    VMW(12);                                                                  \
    BAR();                                                                    \
  } while (0)

  // prologue: B(0)->buf0, B(1)->buf1 (gloads); A(0) via regs->buf0; Areg=A(1);
  // VMW(0) (B landed; AP(1) drain harmless); publish writes; barrier.
  STAGE_B(0, 0, 0); STAGE_B(0, 1, 0);
  STAGE_B(1, 0, 1); STAGE_B(1, 1, 1);
  LOAD_AP(0);
  CVTW_AP(0);
  LOAD_AP(1);
  VMW(0);
  LGKM0();
  BAR();

  for (int i = 0; i < NT; ++i) TILE_P(i, i & 1);
  VMW(0);

  // Epilogue (bias always, scale 1). Same acc mapping as gemm256.
#pragma unroll
  for (int n = 0; n < 4; ++n) {
    const int col = colBase + (n >> 1) * 128 + wn * 32 + (n & 1) * 16 + lr;
    const float bvv = bias[col];
#pragma unroll
    for (int m = 0; m < 8; ++m) {
      const int row0 = rowBase + (m >> 2) * 128 + wm * 64 + (m & 3) * 16 + g0 * 4;
      f32x4 v = acc[m][n];
      if constexpr (OUT_MODE == 0) {
        unsigned short* C = (unsigned short*)Cv;
#pragma unroll
        for (int r = 0; r < 4; ++r)
          C[(size_t)(row0 + r) * N + col] = f2bf(v[r] + bvv);
      } else {  // transposed per-2048-batch: C[b][n][s]
        unsigned short* C = (unsigned short*)Cv;
        const int b = row0 >> 11, s = row0 & 2047;
        u16x4 pk;
#pragma unroll
        for (int r = 0; r < 4; ++r) pk[r] = f2bf(v[r] + bvv);
        *(u16x4*)&C[((size_t)b * N + col) * 2048 + s] = pk;
      }
    }
  }
}

// fp32 -> bf16 for the three DxD weight matrices in one launch.
__global__ __launch_bounds__(256) void conv_w3(
    const float* __restrict__ w0, const float* __restrict__ w1,
    const float* __restrict__ w2, unsigned short* __restrict__ o0,
    unsigned short* __restrict__ o1, unsigned short* __restrict__ o2,
    int n8each) {
  const int tot = 3 * n8each;
  const int stride = gridDim.x * 256;
  for (int i = blockIdx.x * 256 + threadIdx.x; i < tot; i += stride) {
    const float* src;
    unsigned short* dst;
    int k;
    if (i < n8each) { src = w0; dst = o0; k = i; }
    else if (i < 2 * n8each) { src = w1; dst = o1; k = i - n8each; }
    else { src = w2; dst = o2; k = i - 2 * n8each; }
    float4 a = ((const float4*)src)[2 * k];
    float4 b = ((const float4*)src)[2 * k + 1];
    unsigned short h[8];
    h[0] = f2bf(a.x); h[1] = f2bf(a.y); h[2] = f2bf(a.z); h[3] = f2bf(a.w);
    h[4] = f2bf(b.x); h[5] = f2bf(b.y); h[6] = f2bf(b.z); h[7] = f2bf(b.w);
    ((uint4*)dst)[k] = *(uint4*)h;
  }
}

// Row sums of E (FMODE 0 fallback): one block per 2048-elem bf16 row.
__global__ __launch_bounds__(256) void rowsum_kernel(
    const unsigned short* __restrict__ E, float* __restrict__ out) {
  const size_t row = blockIdx.x;
  const unsigned short* p = E + row * 2048;
  const int t = threadIdx.x;
  const int lane = t & 63, wid = t >> 6;

  uint4 x = ((const uint4*)p)[t];
  const unsigned short* hs = (const unsigned short*)&x;
  float s = 0.f;
#pragma unroll
  for (int j = 0; j < 8; ++j) s += bf2f(hs[j]);
#pragma unroll
  for (int d = 1; d < 64; d <<= 1) s += __shfl_xor(s, d);
  __shared__ float red[4];
  if (lane == 0) red[wid] = s;
  __syncthreads();
  if (t == 0) out[row] = red[0] + red[1] + red[2] + red[3];
}

extern "C" void kernel_launch(void* const* d_in, const int* in_sizes, int n_in,
                              void* d_out, int out_size, void* d_ws, size_t ws_size,
                              hipStream_t stream) {
  const float* q_embd = (const float*)d_in[0];
  const float* k_embd = (const float*)d_in[1];
  const float* v_embd = (const float*)d_in[2];
  const float* Wq = (const float*)d_in[3];
  const float* bq = (const float*)d_in[4];
  const float* Wk = (const float*)d_in[5];
  const float* bk = (const float*)d_in[6];
  const float* Wv = (const float*)d_in[7];
  const float* bv = (const float*)d_in[8];

  constexpr int B = 8, QL = 2048, KL = 2048, D = 1024;
  constexpr size_t NE = (size_t)B * QL * D;
  constexpr size_t DD = (size_t)D * D;
  constexpr size_t LAYOUT_BYTES = 3 * NE * 2 + (size_t)B * QL * KL * 2;  // 160 MiB
  constexpr size_t P8_BYTES = (size_t)B * QL * 8 * 4;    // 512 KB (FMODE 1)
  constexpr size_t P32_BYTES = (size_t)B * QL * 32 * 4;  // 2 MB   (FMODE 2)

  unsigned short* qb = (unsigned short*)d_ws;  // [B*QL][D]
  unsigned short* kb = qb + NE;                // [B*KL][D]
  unsigned short* vT = kb + NE;                // [B][D][KL]
  unsigned short* Sb = vT + NE;                // E = exp(S): [B][QL][KL]
  // pre-converted weights live in Sb (dead until QK^T):
  unsigned short* Wqb = Sb;
  unsigned short* Wkb = Sb + DD;
  unsigned short* Wvb = Sb + 2 * DD;

  const int fmode = ws_size >= LAYOUT_BYTES + P32_BYTES ? 2
                  : ws_size >= LAYOUT_BYTES + P8_BYTES  ? 1 : 0;
  float* partial = fmode ? (float*)((char*)d_ws + LAYOUT_BYTES) : (float*)qb;

  dim3 blk256(256), blk512(512);
  const dim3 gproj(4 * 64);  // gx=4, gy=64 -> 256 blocks
  constexpr int NW8 = (int)(DD / 8);

  // --- convert all three weight matrices (6 MB) in one launch ---
  conv_w3<<<dim3(512), blk256, 0, stream>>>(Wq, Wk, Wv, Wqb, Wkb, Wvb, NW8);

  // --- projections with fused fp32->bf16 A-staging ---
  gemmP<0><<<gproj, blk512, 0, stream>>>(q_embd, Wqb, bq, qb, D, D, 4, 64);
  gemmP<0><<<gproj, blk512, 0, stream>>>(k_embd, Wkb, bk, kb, D, D, 4, 64);
  gemmP<1><<<gproj, blk512, 0, stream>>>(v_embd, Wvb, bv, vT, D, D, 4, 64);

  // --- E = exp(Q K^T / sqrt(D)) (no max-sub): 512 blocks ---
  if (fmode == 2) {
    gemm256<3, false, 2><<<dim3(512), blk512, 0, stream>>>(
        qb, kb, nullptr, 0.03125f, Sb, KL, D, (long)QL * D, (long)KL * D,
        (long)QL * KL, partial, 8, 8);
  } else if (fmode == 1) {
    gemm256<3, false, 1><<<dim3(512), blk512, 0, stream>>>(
        qb, kb, nullptr, 0.03125f, Sb, KL, D, (long)QL * D, (long)KL * D,
        (long)QL * KL, partial, 8, 8);
  } else {
    gemm256<3, false, 0><<<dim3(512), blk512, 0, stream>>>(
        qb, kb, nullptr, 0.03125f, Sb, KL, D, (long)QL * D, (long)KL * D,
        (long)QL * KL, nullptr, 8, 8);
    rowsum_kernel<<<dim3(B * QL), blk256, 0, stream>>>(Sb, partial);
  }

  // --- out = (E @ V) / l  (V stored transposed): 256 blocks ---
  if (fmode == 2) {
    gemm256<2, false, 2><<<dim3(256), blk512, 0, stream>>>(
        Sb, vT, nullptr, 1.0f, d_out, D, KL, (long)QL * KL, (long)D * KL,
        (long)QL * D, partial, 4, 8);
  } else if (fmode == 1) {
    gemm256<2, false, 1><<<dim3(256), blk512, 0, stream>>>(
        Sb, vT, nullptr, 1.0f, d_out, D, KL, (long)QL * KL, (long)D * KL,
        (long)QL * D, partial, 4, 8);
  } else {
    gemm256<2, false, 0><<<dim3(256), blk512, 0, stream>>>(
        Sb, vT, nullptr, 1.0f, d_out, D, KL, (long)QL * KL, (long)D * KL,
        (long)QL * D, partial, 4, 8);
  }
}